// Round 1
// baseline (717.955 us; speedup 1.0000x reference)
//
#include <hip/hip_runtime.h>
#include <math.h>

typedef __attribute__((ext_vector_type(4))) float f32x4;
typedef __attribute__((ext_vector_type(8))) short bf16x8;
typedef __attribute__((ext_vector_type(4))) short s16x4;

__device__ __forceinline__ unsigned short f2bf(float f) {
  union { float f; unsigned u; } v; v.f = f;
  return (unsigned short)((v.u + 0x7fffu + ((v.u >> 16) & 1u)) >> 16);
}

// ---------------- LayerNorm: one block per row of 512 ----------------
__global__ void ln_kernel(const float* __restrict__ in, const float* __restrict__ w,
                          const float* __restrict__ b, float* __restrict__ out) {
  __shared__ float sh[4];
  const int t = threadIdx.x;
  const float* p = in + (size_t)blockIdx.x * 512;
  float a0 = p[t], a1 = p[t + 256];
  float s = a0 + a1;
#pragma unroll
  for (int o = 32; o; o >>= 1) s += __shfl_down(s, o);
  if ((t & 63) == 0) sh[t >> 6] = s;
  __syncthreads();
  s = sh[0] + sh[1] + sh[2] + sh[3];
  float mu = s * (1.0f / 512.0f);
  float d0 = a0 - mu, d1 = a1 - mu;
  float q = d0 * d0 + d1 * d1;
  __syncthreads();
#pragma unroll
  for (int o = 32; o; o >>= 1) q += __shfl_down(q, o);
  if ((t & 63) == 0) sh[t >> 6] = q;
  __syncthreads();
  q = sh[0] + sh[1] + sh[2] + sh[3];
  float rstd = rsqrtf(q * (1.0f / 512.0f) + 1e-5f);
  float* po = out + (size_t)blockIdx.x * 512;
  po[t]       = d0 * rstd * w[t] + b[t];
  po[t + 256] = d1 * rstd * w[t + 256] + b[t + 256];
}

// ---- transpose fp32 (K x N, ld=ldi) -> bf16 (N x K, ld=ldo), batched via z ----
__global__ void transpose_w(const float* __restrict__ in, unsigned short* __restrict__ out,
                            int ldi, int ldo, long ibs, long obs) {
  __shared__ float tile[32][33];
  const float* ip = in + (long)blockIdx.z * ibs;
  unsigned short* op = out + (long)blockIdx.z * obs;
  const int tx = threadIdx.x & 31;
  const int ty = threadIdx.x >> 5;  // 0..7
  const int n0 = blockIdx.x * 32, k0 = blockIdx.y * 32;
#pragma unroll
  for (int i = 0; i < 4; ++i)
    tile[ty + i * 8][tx] = ip[(size_t)(k0 + ty + i * 8) * ldi + n0 + tx];
  __syncthreads();
#pragma unroll
  for (int i = 0; i < 4; ++i)
    op[(size_t)(n0 + ty + i * 8) * ldo + k0 + tx] = f2bf(tile[tx][ty + i * 8]);
}

// ---------------- softmax: one block per row of 2048, in place ----------------
__global__ void softmax_kernel(float* __restrict__ attn) {
  __shared__ float sh[4];
  const int t = threadIdx.x;
  float* p = attn + (size_t)blockIdx.x * 2048;
  float v[8];
  float mx = -1e30f;
#pragma unroll
  for (int i = 0; i < 8; ++i) { v[i] = p[t + i * 256]; mx = fmaxf(mx, v[i]); }
#pragma unroll
  for (int o = 32; o; o >>= 1) mx = fmaxf(mx, __shfl_down(mx, o));
  if ((t & 63) == 0) sh[t >> 6] = mx;
  __syncthreads();
  mx = fmaxf(fmaxf(sh[0], sh[1]), fmaxf(sh[2], sh[3]));
  __syncthreads();
  float s = 0.f;
#pragma unroll
  for (int i = 0; i < 8; ++i) { v[i] = __expf(v[i] - mx); s += v[i]; }
#pragma unroll
  for (int o = 32; o; o >>= 1) s += __shfl_down(s, o);
  if ((t & 63) == 0) sh[t >> 6] = s;
  __syncthreads();
  s = sh[0] + sh[1] + sh[2] + sh[3];
  float inv = 1.0f / s;
#pragma unroll
  for (int i = 0; i < 8; ++i) p[t + i * 256] = v[i] * inv;
}

// ---------------- GELU gate: f = gelu_exact(ab[:,2048:]) * ab[:,:2048] ----------------
__global__ void gate_kernel(const float* __restrict__ ab, float* __restrict__ f) {
  size_t i = (size_t)blockIdx.x * 256 + threadIdx.x;  // over 4096*2048
  int m = (int)(i >> 11), j = (int)(i & 2047);
  const float* row = ab + (size_t)m * 4096;
  float a = row[j];
  float bg = row[2048 + j];
  float g = 0.5f * bg * (1.0f + erff(bg * 0.70710678118654752f));
  f[i] = g * a;
}

// ---------------- bf16 MFMA GEMM: C = epi(A @ Bt^T) ----------------
// A: fp32 M x K (lda), staged->bf16. Bt: N x K layout; bf16 (or fp32 if BF32).
// z batching: b = z>>3, h = z&7 with per-operand strides.
// EPI: 0 = +bias; 1 = *scale + rel_bias[h, clip(m-n)+127]; 2 = plain;
//      3 = resid + (acc+bias)*gamma
template <int WM, int WN, int TM, int TN, bool BF32, int EPI>
__global__ __launch_bounds__(256) void gemm_kernel(
    const float* __restrict__ A, const void* __restrict__ Bv, float* __restrict__ C,
    int K, int lda, int ldb, int ldc,
    long sAb, long sAh, long sBb, long sBh, long sCb, long sCh,
    const float* __restrict__ bias, const float* __restrict__ resid,
    const float* __restrict__ gamma, const float* __restrict__ rel, float scale) {
  constexpr int BM = WM * TM * 16;
  constexpr int BN = WN * TN * 16;
  __shared__ short As[BM * 32];
  __shared__ short Bs[BN * 32];

  const int tid = threadIdx.x;
  const int zb = blockIdx.z >> 3, zh = blockIdx.z & 7;
  const float* Ab = A + (long)zb * sAb + (long)zh * sAh;
  float* Cb = C + (long)zb * sCb + (long)zh * sCh;
  const int m0 = blockIdx.y * BM, n0 = blockIdx.x * BN;

  const int w = tid >> 6, lane = tid & 63;
  const int wm = w / WN, wn = w % WN;
  const int lrow = lane & 15, lq = lane >> 4;

  f32x4 acc[TM][TN];
#pragma unroll
  for (int i = 0; i < TM; ++i)
#pragma unroll
    for (int j = 0; j < TN; ++j) acc[i][j] = (f32x4){0.f, 0.f, 0.f, 0.f};

  for (int k0 = 0; k0 < K; k0 += 32) {
    __syncthreads();
    // stage A: fp32 -> bf16 into LDS [BM][32]
#pragma unroll
    for (int it = 0; it < (BM * 8) / 256; ++it) {
      int c = it * 256 + tid;
      int row = c >> 3, col = (c & 7) << 2;
      const float4* src = (const float4*)(Ab + (size_t)(m0 + row) * lda + k0 + col);
      float4 v = *src;
      s16x4 r = {(short)f2bf(v.x), (short)f2bf(v.y), (short)f2bf(v.z), (short)f2bf(v.w)};
      *(s16x4*)(As + row * 32 + col) = r;
    }
    // stage B
    if constexpr (BF32) {
      const float* Bb = (const float*)Bv + (long)zb * sBb + (long)zh * sBh;
#pragma unroll
      for (int it = 0; it < (BN * 8) / 256; ++it) {
        int c = it * 256 + tid;
        int row = c >> 3, col = (c & 7) << 2;
        const float4* src = (const float4*)(Bb + (size_t)(n0 + row) * ldb + k0 + col);
        float4 v = *src;
        s16x4 r = {(short)f2bf(v.x), (short)f2bf(v.y), (short)f2bf(v.z), (short)f2bf(v.w)};
        *(s16x4*)(Bs + row * 32 + col) = r;
      }
    } else {
      const unsigned short* Bb = (const unsigned short*)Bv + (long)zb * sBb + (long)zh * sBh;
#pragma unroll
      for (int it = 0; it < (BN * 4) / 256; ++it) {
        int c = it * 256 + tid;
        int row = c >> 2, col = (c & 3) << 3;
        *(bf16x8*)(Bs + row * 32 + col) =
            *(const bf16x8*)(Bb + (size_t)(n0 + row) * ldb + k0 + col);
      }
    }
    __syncthreads();

    bf16x8 af[TM], bf[TN];
#pragma unroll
    for (int mi = 0; mi < TM; ++mi)
      af[mi] = *(const bf16x8*)(As + (wm * TM * 16 + mi * 16 + lrow) * 32 + lq * 8);
#pragma unroll
    for (int nj = 0; nj < TN; ++nj)
      bf[nj] = *(const bf16x8*)(Bs + (wn * TN * 16 + nj * 16 + lrow) * 32 + lq * 8);
#pragma unroll
    for (int mi = 0; mi < TM; ++mi)
#pragma unroll
      for (int nj = 0; nj < TN; ++nj)
        acc[mi][nj] = __builtin_amdgcn_mfma_f32_16x16x32_bf16(af[mi], bf[nj], acc[mi][nj], 0, 0, 0);
  }

  // epilogue: D row = lq*4 + r, col = lrow (verified gfx950 C/D mapping)
#pragma unroll
  for (int mi = 0; mi < TM; ++mi) {
#pragma unroll
    for (int nj = 0; nj < TN; ++nj) {
      int gm0 = m0 + wm * TM * 16 + mi * 16 + lq * 4;
      int gn = n0 + wn * TN * 16 + nj * 16 + lrow;
#pragma unroll
      for (int r = 0; r < 4; ++r) {
        int gm = gm0 + r;
        size_t idx = (size_t)gm * ldc + gn;
        float v = acc[mi][nj][r];
        if constexpr (EPI == 0) {
          Cb[idx] = v + bias[gn];
        } else if constexpr (EPI == 1) {
          int d = gm - gn;
          d = d < -127 ? -127 : (d > 127 ? 127 : d);
          Cb[idx] = v * scale + rel[zh * 255 + d + 127];
        } else if constexpr (EPI == 2) {
          Cb[idx] = v;
        } else {
          Cb[idx] = resid[idx] + (v + bias[gn]) * gamma[gn];
        }
      }
    }
  }
}

extern "C" void kernel_launch(void* const* d_in, const int* in_sizes, int n_in,
                              void* d_out, int out_size, void* d_ws, size_t ws_size,
                              hipStream_t stream) {
  (void)in_sizes; (void)n_in; (void)out_size; (void)ws_size;
  const float* x        = (const float*)d_in[0];
  const float* ln1_w    = (const float*)d_in[1];
  const float* ln1_b    = (const float*)d_in[2];
  const float* qkv_w    = (const float*)d_in[3];
  const float* qkv_b    = (const float*)d_in[4];
  const float* out_w    = (const float*)d_in[5];
  const float* out_b    = (const float*)d_in[6];
  const float* rel_bias = (const float*)d_in[7];
  const float* gamma1   = (const float*)d_in[8];
  const float* ln2_w    = (const float*)d_in[9];
  const float* ln2_b    = (const float*)d_in[10];
  const float* ffn_in_w = (const float*)d_in[11];
  const float* ffn_in_b = (const float*)d_in[12];
  const float* ffn_out_w  = (const float*)d_in[13];
  const float* ffn_out_b  = (const float*)d_in[14];
  const float* gamma2   = (const float*)d_in[15];

  float* x_out = (float*)d_out;                       // (2,2048,512)
  float* attn  = x_out + (size_t)2 * 2048 * 512;      // (2,8,2048,2048)

  // workspace layout (floats)
  float* ws  = (float*)d_ws;
  float* h   = ws;                  // 4096x512   (LN1 out, reused for LN2 out)
  float* qkv = h + 2097152;         // 4096x1536
  float* o   = qkv + 6291456;       // 4096x512
  float* x1  = o + 2097152;         // 4096x512
  float* ab  = x1 + 2097152;        // 4096x4096
  float* f   = ab + 16777216;       // 4096x2048
  unsigned short* bt_qkv  = (unsigned short*)(f + 8388608);  // 1536x512
  unsigned short* bt_out  = bt_qkv + 786432;                 // 512x512
  unsigned short* bt_ffn1 = bt_out + 262144;                 // 4096x512
  unsigned short* bt_ffn2 = bt_ffn1 + 2097152;               // 512x2048
  unsigned short* vt      = bt_ffn2 + 1048576;               // 16 x 64 x 2048

  // weight transposes (fp32 KxN -> bf16 NxK)
  transpose_w<<<dim3(48, 16, 1), 256, 0, stream>>>(qkv_w,     bt_qkv,  1536, 512,  0, 0);
  transpose_w<<<dim3(16, 16, 1), 256, 0, stream>>>(out_w,     bt_out,  512,  512,  0, 0);
  transpose_w<<<dim3(128, 16, 1), 256, 0, stream>>>(ffn_in_w, bt_ffn1, 4096, 512,  0, 0);
  transpose_w<<<dim3(16, 64, 1), 256, 0, stream>>>(ffn_out_w, bt_ffn2, 512,  2048, 0, 0);

  // LN1: x -> h
  ln_kernel<<<4096, 256, 0, stream>>>(x, ln1_w, ln1_b, h);

  // QKV GEMM: qkv = h @ qkv_w + qkv_b   (4096x1536, K=512)
  gemm_kernel<2, 2, 4, 4, false, 0><<<dim3(12, 32, 1), 256, 0, stream>>>(
      h, bt_qkv, qkv, 512, 512, 512, 1536, 0, 0, 0, 0, 0, 0,
      qkv_b, nullptr, nullptr, nullptr, 0.f);

  // V^T extraction: vt[bh][d][l] (bf16)
  transpose_w<<<dim3(2, 64, 8), 256, 0, stream>>>(
      qkv + 1024, vt, 1536, 2048, 64, (long)64 * 2048);
  transpose_w<<<dim3(2, 64, 8), 256, 0, stream>>>(
      qkv + (size_t)2048 * 1536 + 1024, vt + (size_t)8 * 64 * 2048, 1536, 2048, 64,
      (long)64 * 2048);

  // scores = Q @ K^T * scale + rel_bias  -> attn region (per b,h; z=16)
  gemm_kernel<2, 2, 4, 4, true, 1><<<dim3(16, 16, 16), 256, 0, stream>>>(
      qkv, qkv + 512, attn, 64, 1536, 1536, 2048,
      (long)2048 * 1536, 64, (long)2048 * 1536, 64,
      (long)8 * 2048 * 2048, (long)2048 * 2048,
      nullptr, nullptr, nullptr, rel_bias, 0.125f);

  // softmax rows in place
  softmax_kernel<<<32768, 256, 0, stream>>>(attn);

  // PV: o = attn @ V   (per b,h; M=2048, N=64, K=2048)
  gemm_kernel<4, 1, 2, 4, false, 2><<<dim3(1, 16, 16), 256, 0, stream>>>(
      attn, vt, o, 2048, 2048, 2048, 512,
      (long)8 * 2048 * 2048, (long)2048 * 2048,
      (long)8 * 64 * 2048, (long)64 * 2048,
      (long)2048 * 512, 64,
      nullptr, nullptr, nullptr, nullptr, 0.f);

  // out proj + residual: x1 = x + (o @ out_w + out_b) * gamma1
  gemm_kernel<2, 2, 4, 4, false, 3><<<dim3(4, 32, 1), 256, 0, stream>>>(
      o, bt_out, x1, 512, 512, 512, 512, 0, 0, 0, 0, 0, 0,
      out_b, x, gamma1, nullptr, 0.f);

  // LN2: x1 -> h
  ln_kernel<<<4096, 256, 0, stream>>>(x1, ln2_w, ln2_b, h);

  // FFN1: ab = h @ ffn_in_w + ffn_in_b  (4096x4096, K=512)
  gemm_kernel<2, 2, 4, 4, false, 0><<<dim3(32, 32, 1), 256, 0, stream>>>(
      h, bt_ffn1, ab, 512, 512, 512, 4096, 0, 0, 0, 0, 0, 0,
      ffn_in_b, nullptr, nullptr, nullptr, 0.f);

  // gate: f = gelu(ab[:,2048:]) * ab[:,:2048]
  gate_kernel<<<32768, 256, 0, stream>>>(ab, f);

  // FFN2 + residual: x_out = x1 + (f @ ffn_out_w + ffn_out_b) * gamma2
  gemm_kernel<2, 2, 4, 4, false, 3><<<dim3(4, 32, 1), 256, 0, stream>>>(
      f, bt_ffn2, x_out, 2048, 2048, 2048, 512, 0, 0, 0, 0, 0, 0,
      ffn_out_b, x1, gamma2, nullptr, 0.f);
}

// Round 2
// 641.708 us; speedup vs baseline: 1.1188x; 1.1188x over previous
//
#include <hip/hip_runtime.h>
#include <math.h>

typedef __attribute__((ext_vector_type(4))) float f32x4;
typedef __attribute__((ext_vector_type(8))) short bf16x8;
typedef __attribute__((ext_vector_type(4))) short s16x4;

__device__ __forceinline__ unsigned short f2bf(float f) {
  union { float f; unsigned u; } v; v.f = f;
  return (unsigned short)((v.u + 0x7fffu + ((v.u >> 16) & 1u)) >> 16);
}

// ---------------- LayerNorm: one block per row of 512 ----------------
__global__ void ln_kernel(const float* __restrict__ in, const float* __restrict__ w,
                          const float* __restrict__ b, float* __restrict__ out) {
  __shared__ float sh[4];
  const int t = threadIdx.x;
  const float* p = in + (size_t)blockIdx.x * 512;
  float a0 = p[t], a1 = p[t + 256];
  float s = a0 + a1;
#pragma unroll
  for (int o = 32; o; o >>= 1) s += __shfl_down(s, o);
  if ((t & 63) == 0) sh[t >> 6] = s;
  __syncthreads();
  s = sh[0] + sh[1] + sh[2] + sh[3];
  float mu = s * (1.0f / 512.0f);
  float d0 = a0 - mu, d1 = a1 - mu;
  float q = d0 * d0 + d1 * d1;
  __syncthreads();
#pragma unroll
  for (int o = 32; o; o >>= 1) q += __shfl_down(q, o);
  if ((t & 63) == 0) sh[t >> 6] = q;
  __syncthreads();
  q = sh[0] + sh[1] + sh[2] + sh[3];
  float rstd = rsqrtf(q * (1.0f / 512.0f) + 1e-5f);
  float* po = out + (size_t)blockIdx.x * 512;
  po[t]       = d0 * rstd * w[t] + b[t];
  po[t + 256] = d1 * rstd * w[t + 256] + b[t + 256];
}

// ---- transpose fp32 (K x N, ld=ldi) -> bf16 (N x K, ld=ldo), batched via z ----
__global__ void transpose_w(const float* __restrict__ in, unsigned short* __restrict__ out,
                            int ldi, int ldo, long ibs, long obs) {
  __shared__ float tile[32][33];
  const float* ip = in + (long)blockIdx.z * ibs;
  unsigned short* op = out + (long)blockIdx.z * obs;
  const int tx = threadIdx.x & 31;
  const int ty = threadIdx.x >> 5;  // 0..7
  const int n0 = blockIdx.x * 32, k0 = blockIdx.y * 32;
#pragma unroll
  for (int i = 0; i < 4; ++i)
    tile[ty + i * 8][tx] = ip[(size_t)(k0 + ty + i * 8) * ldi + n0 + tx];
  __syncthreads();
#pragma unroll
  for (int i = 0; i < 4; ++i)
    op[(size_t)(n0 + ty + i * 8) * ldo + k0 + tx] = f2bf(tile[tx][ty + i * 8]);
}

// ---------------- bf16 MFMA GEMM: C = epi(A @ Bt^T) ----------------
// A: fp32 M x K (lda), staged->bf16. Bt: N x K bf16.
// EPI: 0 = +bias; 3 = resid + (acc+bias)*gamma
template <int WM, int WN, int TM, int TN, int EPI>
__global__ __launch_bounds__(256) void gemm_kernel(
    const float* __restrict__ A, const unsigned short* __restrict__ Bt,
    float* __restrict__ C, int K, int lda, int ldb, int ldc,
    const float* __restrict__ bias, const float* __restrict__ resid,
    const float* __restrict__ gamma) {
  constexpr int BM = WM * TM * 16;
  constexpr int BN = WN * TN * 16;
  __shared__ short As[BM * 32];
  __shared__ short Bs[BN * 32];

  const int tid = threadIdx.x;
  const int m0 = blockIdx.y * BM, n0 = blockIdx.x * BN;
  const int w = tid >> 6, lane = tid & 63;
  const int wm = w / WN, wn = w % WN;
  const int lrow = lane & 15, lq = lane >> 4;

  f32x4 acc[TM][TN];
#pragma unroll
  for (int i = 0; i < TM; ++i)
#pragma unroll
    for (int j = 0; j < TN; ++j) acc[i][j] = (f32x4){0.f, 0.f, 0.f, 0.f};

  for (int k0 = 0; k0 < K; k0 += 32) {
    __syncthreads();
#pragma unroll
    for (int it = 0; it < (BM * 8) / 256; ++it) {
      int c = it * 256 + tid;
      int row = c >> 3, col = (c & 7) << 2;
      float4 v = *(const float4*)(A + (size_t)(m0 + row) * lda + k0 + col);
      s16x4 r = {(short)f2bf(v.x), (short)f2bf(v.y), (short)f2bf(v.z), (short)f2bf(v.w)};
      *(s16x4*)(As + row * 32 + col) = r;
    }
#pragma unroll
    for (int it = 0; it < (BN * 4) / 256; ++it) {
      int c = it * 256 + tid;
      int row = c >> 2, col = (c & 3) << 3;
      *(bf16x8*)(Bs + row * 32 + col) =
          *(const bf16x8*)(Bt + (size_t)(n0 + row) * ldb + k0 + col);
    }
    __syncthreads();

    bf16x8 af[TM], bf[TN];
#pragma unroll
    for (int mi = 0; mi < TM; ++mi)
      af[mi] = *(const bf16x8*)(As + (wm * TM * 16 + mi * 16 + lrow) * 32 + lq * 8);
#pragma unroll
    for (int nj = 0; nj < TN; ++nj)
      bf[nj] = *(const bf16x8*)(Bs + (wn * TN * 16 + nj * 16 + lrow) * 32 + lq * 8);
#pragma unroll
    for (int mi = 0; mi < TM; ++mi)
#pragma unroll
      for (int nj = 0; nj < TN; ++nj)
        acc[mi][nj] = __builtin_amdgcn_mfma_f32_16x16x32_bf16(af[mi], bf[nj], acc[mi][nj], 0, 0, 0);
  }

#pragma unroll
  for (int mi = 0; mi < TM; ++mi) {
#pragma unroll
    for (int nj = 0; nj < TN; ++nj) {
      int gm0 = m0 + wm * TM * 16 + mi * 16 + lq * 4;
      int gn = n0 + wn * TN * 16 + nj * 16 + lrow;
#pragma unroll
      for (int r = 0; r < 4; ++r) {
        int gm = gm0 + r;
        size_t idx = (size_t)gm * ldc + gn;
        float v = acc[mi][nj][r];
        if constexpr (EPI == 0) {
          C[idx] = v + bias[gn];
        } else {
          C[idx] = resid[idx] + (v + bias[gn]) * gamma[gn];
        }
      }
    }
  }
}

// --------- FFN1 + GELU gate fused: f = gelu(h@Wb + bb) * (h@Wa + ba) ---------
// Wa = ffn_in_w cols [0,2048), Wb = cols [2048,4096). BM=128, BN=64 (per half).
__global__ __launch_bounds__(256) void ffn1_gate_kernel(
    const float* __restrict__ A, const unsigned short* __restrict__ Bt,
    float* __restrict__ F, const float* __restrict__ bias) {
  __shared__ short As[128 * 32];
  __shared__ short Bs[64 * 32];
  __shared__ short Bs2[64 * 32];

  const int tid = threadIdx.x;
  const int n0 = blockIdx.x * 64, m0 = blockIdx.y * 128;
  const int w = tid >> 6, lane = tid & 63;
  const int wm = w >> 1, wn = w & 1;
  const int lrow = lane & 15, lq = lane >> 4;

  f32x4 acca[4][2], accb[4][2];
#pragma unroll
  for (int i = 0; i < 4; ++i)
#pragma unroll
    for (int j = 0; j < 2; ++j) {
      acca[i][j] = (f32x4){0.f, 0.f, 0.f, 0.f};
      accb[i][j] = (f32x4){0.f, 0.f, 0.f, 0.f};
    }

  for (int k0 = 0; k0 < 512; k0 += 32) {
    __syncthreads();
#pragma unroll
    for (int it = 0; it < 4; ++it) {
      int c = it * 256 + tid;
      int row = c >> 3, col = (c & 7) << 2;
      float4 v = *(const float4*)(A + (size_t)(m0 + row) * 512 + k0 + col);
      s16x4 r = {(short)f2bf(v.x), (short)f2bf(v.y), (short)f2bf(v.z), (short)f2bf(v.w)};
      *(s16x4*)(As + row * 32 + col) = r;
    }
    {
      int row = tid >> 2, col = (tid & 3) << 3;
      *(bf16x8*)(Bs + row * 32 + col) =
          *(const bf16x8*)(Bt + (size_t)(n0 + row) * 512 + k0 + col);
      *(bf16x8*)(Bs2 + row * 32 + col) =
          *(const bf16x8*)(Bt + (size_t)(2048 + n0 + row) * 512 + k0 + col);
    }
    __syncthreads();

    bf16x8 af[4], ba[2], bb[2];
#pragma unroll
    for (int mi = 0; mi < 4; ++mi)
      af[mi] = *(const bf16x8*)(As + (wm * 64 + mi * 16 + lrow) * 32 + lq * 8);
#pragma unroll
    for (int nj = 0; nj < 2; ++nj) {
      ba[nj] = *(const bf16x8*)(Bs + (wn * 32 + nj * 16 + lrow) * 32 + lq * 8);
      bb[nj] = *(const bf16x8*)(Bs2 + (wn * 32 + nj * 16 + lrow) * 32 + lq * 8);
    }
#pragma unroll
    for (int mi = 0; mi < 4; ++mi)
#pragma unroll
      for (int nj = 0; nj < 2; ++nj) {
        acca[mi][nj] = __builtin_amdgcn_mfma_f32_16x16x32_bf16(af[mi], ba[nj], acca[mi][nj], 0, 0, 0);
        accb[mi][nj] = __builtin_amdgcn_mfma_f32_16x16x32_bf16(af[mi], bb[nj], accb[mi][nj], 0, 0, 0);
      }
  }

#pragma unroll
  for (int mi = 0; mi < 4; ++mi)
#pragma unroll
    for (int nj = 0; nj < 2; ++nj) {
      int gm0 = m0 + wm * 64 + mi * 16 + lq * 4;
      int gn = n0 + wn * 32 + nj * 16 + lrow;
#pragma unroll
      for (int r = 0; r < 4; ++r) {
        float a = acca[mi][nj][r] + bias[gn];
        float bg = accb[mi][nj][r] + bias[2048 + gn];
        float g = 0.5f * bg * (1.0f + erff(bg * 0.70710678118654752f));
        F[(size_t)(gm0 + r) * 2048 + gn] = g * a;
      }
    }
}

// --------- Fused attention: S=QK^T (recompute), softmax, write attn, O=PV ---------
// One block: 64 query rows x one (b,h). 256 threads = 4 waves (2x2 over 64x128 S tile).
__global__ __launch_bounds__(256) void attn_fused(
    const float* __restrict__ qkv, const unsigned short* __restrict__ vt,
    const float* __restrict__ rel, float* __restrict__ attn, float* __restrict__ o) {
  __shared__ short q_lds[2 * 64 * 32];   // [d-chunk][q][d&31]
  __shared__ short k_lds[2 * 128 * 32];  // [d-chunk][key][d&31]
  __shared__ short p_lds[4 * 64 * 32];   // [key-chunk][q][key&31]
  __shared__ short v_lds[4 * 64 * 32];   // [key-chunk][d][key&31]
  __shared__ float rsum[64];
  __shared__ float rinv[64];

  const int tid = threadIdx.x;
  const int m0 = blockIdx.x * 64;
  const int bh = blockIdx.y;
  const int b = bh >> 3, h = bh & 7;
  const float* qbase = qkv + (size_t)(b * 2048) * 1536 + h * 64;
  const float* kbase = qbase + 512;
  const unsigned short* vbase = vt + (size_t)bh * 64 * 2048;
  float* abase = attn + (size_t)bh * 2048 * 2048;
  const float* relh = rel + h * 255;

  const int w = tid >> 6, lane = tid & 63;
  const int wm = w >> 1, wn = w & 1;
  const int lrow = lane & 15, lq = lane >> 4;

  // stage Q once: 64 x 64 fp32 -> bf16
#pragma unroll
  for (int it = 0; it < 4; ++it) {
    int idx = it * 256 + tid;
    int row = idx >> 4, c4 = (idx & 15) << 2;
    float4 v = *(const float4*)(qbase + (size_t)(m0 + row) * 1536 + c4);
    s16x4 r = {(short)f2bf(v.x), (short)f2bf(v.y), (short)f2bf(v.z), (short)f2bf(v.w)};
    *(s16x4*)(q_lds + (c4 >> 5) * 2048 + row * 32 + (c4 & 31)) = r;
  }
  if (tid < 64) rsum[tid] = 0.f;

  float psum[2][4] = {{0.f, 0.f, 0.f, 0.f}, {0.f, 0.f, 0.f, 0.f}};

  // ---- pass 1: row sums of exp(s) ----
  for (int t = 0; t < 16; ++t) {
    const int kt0 = t * 128;
    __syncthreads();
#pragma unroll
    for (int it = 0; it < 8; ++it) {
      int idx = it * 256 + tid;
      int row = idx >> 4, c4 = (idx & 15) << 2;
      float4 v = *(const float4*)(kbase + (size_t)(kt0 + row) * 1536 + c4);
      s16x4 r = {(short)f2bf(v.x), (short)f2bf(v.y), (short)f2bf(v.z), (short)f2bf(v.w)};
      *(s16x4*)(k_lds + (c4 >> 5) * 4096 + row * 32 + (c4 & 31)) = r;
    }
    __syncthreads();

    f32x4 acc[2][4];
#pragma unroll
    for (int mi = 0; mi < 2; ++mi)
#pragma unroll
      for (int nj = 0; nj < 4; ++nj) acc[mi][nj] = (f32x4){0.f, 0.f, 0.f, 0.f};
#pragma unroll
    for (int c = 0; c < 2; ++c) {
      bf16x8 af[2], bfv[4];
#pragma unroll
      for (int mi = 0; mi < 2; ++mi)
        af[mi] = *(const bf16x8*)(q_lds + c * 2048 + (wm * 32 + mi * 16 + lrow) * 32 + lq * 8);
#pragma unroll
      for (int nj = 0; nj < 4; ++nj)
        bfv[nj] = *(const bf16x8*)(k_lds + c * 4096 + (wn * 64 + nj * 16 + lrow) * 32 + lq * 8);
#pragma unroll
      for (int mi = 0; mi < 2; ++mi)
#pragma unroll
        for (int nj = 0; nj < 4; ++nj)
          acc[mi][nj] = __builtin_amdgcn_mfma_f32_16x16x32_bf16(af[mi], bfv[nj], acc[mi][nj], 0, 0, 0);
    }
#pragma unroll
    for (int mi = 0; mi < 2; ++mi)
#pragma unroll
      for (int nj = 0; nj < 4; ++nj) {
        int kl = wn * 64 + nj * 16 + lrow;
#pragma unroll
        for (int r = 0; r < 4; ++r) {
          int r_loc = wm * 32 + mi * 16 + lq * 4 + r;
          int d = (m0 + r_loc) - (kt0 + kl);
          d = d < -127 ? -127 : (d > 127 ? 127 : d);
          float s = acc[mi][nj][r] * 0.125f + relh[d + 127];
          psum[mi][r] += __expf(s);
        }
      }
  }
  // cross-lane reduce over the 16 'lrow' lanes
#pragma unroll
  for (int off = 1; off < 16; off <<= 1)
#pragma unroll
    for (int mi = 0; mi < 2; ++mi)
#pragma unroll
      for (int r = 0; r < 4; ++r) psum[mi][r] += __shfl_xor(psum[mi][r], off);
  if (lrow == 0) {
#pragma unroll
    for (int mi = 0; mi < 2; ++mi)
#pragma unroll
      for (int r = 0; r < 4; ++r)
        atomicAdd(&rsum[wm * 32 + mi * 16 + lq * 4 + r], psum[mi][r]);
  }
  __syncthreads();
  if (tid < 64) rinv[tid] = 1.0f / rsum[tid];
  __syncthreads();
  float rv[2][4];
#pragma unroll
  for (int mi = 0; mi < 2; ++mi)
#pragma unroll
    for (int r = 0; r < 4; ++r) rv[mi][r] = rinv[wm * 32 + mi * 16 + lq * 4 + r];

  // ---- pass 2: recompute S, write normalized attn, accumulate O = P @ V ----
  f32x4 oacc[2][2];
#pragma unroll
  for (int mi = 0; mi < 2; ++mi)
#pragma unroll
    for (int nj = 0; nj < 2; ++nj) oacc[mi][nj] = (f32x4){0.f, 0.f, 0.f, 0.f};

  for (int t = 0; t < 16; ++t) {
    const int kt0 = t * 128;
    __syncthreads();
#pragma unroll
    for (int it = 0; it < 8; ++it) {
      int idx = it * 256 + tid;
      int row = idx >> 4, c4 = (idx & 15) << 2;
      float4 v = *(const float4*)(kbase + (size_t)(kt0 + row) * 1536 + c4);
      s16x4 r = {(short)f2bf(v.x), (short)f2bf(v.y), (short)f2bf(v.z), (short)f2bf(v.w)};
      *(s16x4*)(k_lds + (c4 >> 5) * 4096 + row * 32 + (c4 & 31)) = r;
    }
#pragma unroll
    for (int it = 0; it < 4; ++it) {
      int idx = it * 256 + tid;
      int dd = idx >> 4, c8 = (idx & 15) << 3;
      *(bf16x8*)(v_lds + (c8 >> 5) * 2048 + dd * 32 + (c8 & 31)) =
          *(const bf16x8*)(vbase + (size_t)dd * 2048 + kt0 + c8);
    }
    __syncthreads();

    f32x4 acc[2][4];
#pragma unroll
    for (int mi = 0; mi < 2; ++mi)
#pragma unroll
      for (int nj = 0; nj < 4; ++nj) acc[mi][nj] = (f32x4){0.f, 0.f, 0.f, 0.f};
#pragma unroll
    for (int c = 0; c < 2; ++c) {
      bf16x8 af[2], bfv[4];
#pragma unroll
      for (int mi = 0; mi < 2; ++mi)
        af[mi] = *(const bf16x8*)(q_lds + c * 2048 + (wm * 32 + mi * 16 + lrow) * 32 + lq * 8);
#pragma unroll
      for (int nj = 0; nj < 4; ++nj)
        bfv[nj] = *(const bf16x8*)(k_lds + c * 4096 + (wn * 64 + nj * 16 + lrow) * 32 + lq * 8);
#pragma unroll
      for (int mi = 0; mi < 2; ++mi)
#pragma unroll
        for (int nj = 0; nj < 4; ++nj)
          acc[mi][nj] = __builtin_amdgcn_mfma_f32_16x16x32_bf16(af[mi], bfv[nj], acc[mi][nj], 0, 0, 0);
    }
#pragma unroll
    for (int mi = 0; mi < 2; ++mi)
#pragma unroll
      for (int nj = 0; nj < 4; ++nj) {
        int kl = wn * 64 + nj * 16 + lrow;
#pragma unroll
        for (int r = 0; r < 4; ++r) {
          int r_loc = wm * 32 + mi * 16 + lq * 4 + r;
          int d = (m0 + r_loc) - (kt0 + kl);
          d = d < -127 ? -127 : (d > 127 ? 127 : d);
          float s = acc[mi][nj][r] * 0.125f + relh[d + 127];
          float e = __expf(s) * rv[mi][r];
          __builtin_nontemporal_store(e, abase + (size_t)(m0 + r_loc) * 2048 + kt0 + kl);
          p_lds[(kl >> 5) * 2048 + r_loc * 32 + (kl & 31)] = (short)f2bf(e);
        }
      }
    __syncthreads();

#pragma unroll
    for (int c2 = 0; c2 < 4; ++c2) {
      bf16x8 ap[2], bv[2];
#pragma unroll
      for (int mi = 0; mi < 2; ++mi)
        ap[mi] = *(const bf16x8*)(p_lds + c2 * 2048 + (wm * 32 + mi * 16 + lrow) * 32 + lq * 8);
#pragma unroll
      for (int nj = 0; nj < 2; ++nj)
        bv[nj] = *(const bf16x8*)(v_lds + c2 * 2048 + (wn * 32 + nj * 16 + lrow) * 32 + lq * 8);
#pragma unroll
      for (int mi = 0; mi < 2; ++mi)
#pragma unroll
        for (int nj = 0; nj < 2; ++nj)
          oacc[mi][nj] = __builtin_amdgcn_mfma_f32_16x16x32_bf16(ap[mi], bv[nj], oacc[mi][nj], 0, 0, 0);
    }
  }

  // write O (b, l, h, d)
#pragma unroll
  for (int mi = 0; mi < 2; ++mi)
#pragma unroll
    for (int nj = 0; nj < 2; ++nj) {
      int dd = wn * 32 + nj * 16 + lrow;
#pragma unroll
      for (int r = 0; r < 4; ++r) {
        int rr = m0 + wm * 32 + mi * 16 + lq * 4 + r;
        o[(size_t)(b * 2048 + rr) * 512 + h * 64 + dd] = oacc[mi][nj][r];
      }
    }
}

extern "C" void kernel_launch(void* const* d_in, const int* in_sizes, int n_in,
                              void* d_out, int out_size, void* d_ws, size_t ws_size,
                              hipStream_t stream) {
  (void)in_sizes; (void)n_in; (void)out_size; (void)ws_size;
  const float* x        = (const float*)d_in[0];
  const float* ln1_w    = (const float*)d_in[1];
  const float* ln1_b    = (const float*)d_in[2];
  const float* qkv_w    = (const float*)d_in[3];
  const float* qkv_b    = (const float*)d_in[4];
  const float* out_w    = (const float*)d_in[5];
  const float* out_b    = (const float*)d_in[6];
  const float* rel_bias = (const float*)d_in[7];
  const float* gamma1   = (const float*)d_in[8];
  const float* ln2_w    = (const float*)d_in[9];
  const float* ln2_b    = (const float*)d_in[10];
  const float* ffn_in_w = (const float*)d_in[11];
  const float* ffn_in_b = (const float*)d_in[12];
  const float* ffn_out_w  = (const float*)d_in[13];
  const float* ffn_out_b  = (const float*)d_in[14];
  const float* gamma2   = (const float*)d_in[15];

  float* x_out = (float*)d_out;                       // (2,2048,512)
  float* attn  = x_out + (size_t)2 * 2048 * 512;      // (2,8,2048,2048)

  // workspace layout (floats)
  float* ws  = (float*)d_ws;
  float* h   = ws;                  // 4096x512   (LN1 out, reused for LN2 out)
  float* qkv = h + 2097152;         // 4096x1536
  float* o   = qkv + 6291456;       // 4096x512
  float* x1  = o + 2097152;         // 4096x512
  float* f   = x1 + 2097152;        // 4096x2048
  unsigned short* bt_qkv  = (unsigned short*)(f + 8388608);  // 1536x512
  unsigned short* bt_out  = bt_qkv + 786432;                 // 512x512
  unsigned short* bt_ffn1 = bt_out + 262144;                 // 4096x512
  unsigned short* bt_ffn2 = bt_ffn1 + 2097152;               // 512x2048
  unsigned short* vt      = bt_ffn2 + 1048576;               // 16 x 64 x 2048

  // weight transposes (fp32 KxN -> bf16 NxK)
  transpose_w<<<dim3(48, 16, 1), 256, 0, stream>>>(qkv_w,     bt_qkv,  1536, 512,  0, 0);
  transpose_w<<<dim3(16, 16, 1), 256, 0, stream>>>(out_w,     bt_out,  512,  512,  0, 0);
  transpose_w<<<dim3(128, 16, 1), 256, 0, stream>>>(ffn_in_w, bt_ffn1, 4096, 512,  0, 0);
  transpose_w<<<dim3(16, 64, 1), 256, 0, stream>>>(ffn_out_w, bt_ffn2, 512,  2048, 0, 0);

  // LN1: x -> h
  ln_kernel<<<4096, 256, 0, stream>>>(x, ln1_w, ln1_b, h);

  // QKV GEMM: qkv = h @ qkv_w + qkv_b   (4096x1536, K=512)
  gemm_kernel<2, 2, 4, 4, 0><<<dim3(12, 32, 1), 256, 0, stream>>>(
      h, bt_qkv, qkv, 512, 512, 512, 1536, qkv_b, nullptr, nullptr);

  // V^T extraction: vt[bh][d][l] (bf16)
  transpose_w<<<dim3(2, 64, 8), 256, 0, stream>>>(
      qkv + 1024, vt, 1536, 2048, 64, (long)64 * 2048);
  transpose_w<<<dim3(2, 64, 8), 256, 0, stream>>>(
      qkv + (size_t)2048 * 1536 + 1024, vt + (size_t)8 * 64 * 2048, 1536, 2048, 64,
      (long)64 * 2048);

  // fused attention: softmax(QK^T*scale + rel) -> attn (d_out), O=PV -> o
  attn_fused<<<dim3(32, 16, 1), 256, 0, stream>>>(qkv, vt, rel_bias, attn, o);

  // out proj + residual: x1 = x + (o @ out_w + out_b) * gamma1
  gemm_kernel<2, 2, 4, 4, 3><<<dim3(4, 32, 1), 256, 0, stream>>>(
      o, bt_out, x1, 512, 512, 512, 512, out_b, x, gamma1);

  // LN2: x1 -> h
  ln_kernel<<<4096, 256, 0, stream>>>(x1, ln2_w, ln2_b, h);

  // FFN1 + gate fused: f = gelu(h@Wb+bb) * (h@Wa+ba)
  ffn1_gate_kernel<<<dim3(32, 32, 1), 256, 0, stream>>>(h, bt_ffn1, f, ffn_in_b);

  // FFN2 + residual: x_out = x1 + (f @ ffn_out_w + ffn_out_b) * gamma2
  gemm_kernel<2, 2, 4, 4, 3><<<dim3(4, 32, 1), 256, 0, stream>>>(
      f, bt_ffn2, x_out, 2048, 2048, 2048, 512, ffn_out_b, x1, gamma2);
}